// Round 1
// 887.234 us; speedup vs baseline: 1.0615x; 1.0615x over previous
//
#include <hip/hip_runtime.h>

#define Bb 2
#define Hh 16
#define Ss 2048
#define Dd 128
#define NWrd (Ss / 64)
#define NBLK (Bb * Hh * (Ss / 64))  // 1024 total workgroups

typedef _Float16 half_t;
typedef __attribute__((ext_vector_type(4))) float floatx4;
typedef __attribute__((ext_vector_type(8))) _Float16 halfx8;
typedef unsigned long long u64;

// ---- cast Q (scale folded) and K to f16 ----
__global__ __launch_bounds__(256) void cvt_qk_kernel(
    const float* __restrict__ Q, const float* __restrict__ K,
    const float* __restrict__ scale_p,
    half_t* __restrict__ Qh, half_t* __restrict__ Kh) {
  const float s = scale_p[0];
  size_t i = ((size_t)blockIdx.x * 256 + threadIdx.x) * 8;
  floatx4 a0 = *(const floatx4*)(Q + i);
  floatx4 a1 = *(const floatx4*)(Q + i + 4);
  halfx8 hq = {(half_t)(a0.x * s), (half_t)(a0.y * s), (half_t)(a0.z * s),
               (half_t)(a0.w * s), (half_t)(a1.x * s), (half_t)(a1.y * s),
               (half_t)(a1.z * s), (half_t)(a1.w * s)};
  *(halfx8*)(Qh + i) = hq;
  floatx4 b0 = *(const floatx4*)(K + i);
  floatx4 b1 = *(const floatx4*)(K + i + 4);
  halfx8 hk = {(half_t)b0.x, (half_t)b0.y, (half_t)b0.z, (half_t)b0.w,
               (half_t)b1.x, (half_t)b1.y, (half_t)b1.z, (half_t)b1.w};
  *(halfx8*)(Kh + i) = hk;
}

// ---- V transpose+cast: [B*H, S, D] f32 -> [B*H, D, S] f16 ----
__global__ __launch_bounds__(256) void vt_kernel(const float* __restrict__ V,
                                                 half_t* __restrict__ Vt) {
  __shared__ __align__(16) half_t t[64 * 72];
  const int bh = blockIdx.z;
  const int k0 = blockIdx.x * 64;
  const int d0 = blockIdx.y * 64;
  const int tid = threadIdx.x;
  const float* src = V + ((size_t)bh * Ss + k0) * Dd + d0;
  for (int idx = tid; idx < 64 * 16; idx += 256) {
    int r = idx >> 4;
    int c4 = (idx & 15) << 2;
    floatx4 v = *(const floatx4*)(src + (size_t)r * Dd + c4);
    t[(c4 + 0) * 72 + r] = (half_t)v.x;
    t[(c4 + 1) * 72 + r] = (half_t)v.y;
    t[(c4 + 2) * 72 + r] = (half_t)v.z;
    t[(c4 + 3) * 72 + r] = (half_t)v.w;
  }
  __syncthreads();
  half_t* dst = Vt + ((size_t)bh * Dd + d0) * Ss + k0;
  for (int idx = tid; idx < 64 * 8; idx += 256) {
    int r = idx >> 3;
    int c8 = (idx & 7) << 3;
    *(halfx8*)(dst + (size_t)r * Ss + c8) = *(const halfx8*)&t[r * 72 + c8];
  }
}

// ---- pack mask ints -> bit words (one wave per 64 columns) ----
__global__ __launch_bounds__(256) void mask_pack_kernel(
    const int* __restrict__ mask, u64* __restrict__ mb) {
  size_t w = (size_t)blockIdx.x * 4 + (threadIdx.x >> 6);
  int lane = threadIdx.x & 63;
  int m = mask[w * 64 + lane];
  u64 bal = __ballot(m != 0);
  if (lane == 0) mb[w] = bal;
}

// ---- fused attention ----
// LDS: K tile only (single buffer, register-prefetched) + Ps transpose scratch.
// V B-fragments and Q A-fragments load directly from global (L2-resident).
__global__ __launch_bounds__(256, 4) void attn_kernel(
    const half_t* __restrict__ Qh, const half_t* __restrict__ Kh,
    const u64* __restrict__ Mb, const half_t* __restrict__ Vt,
    float* __restrict__ ctx_out, float* __restrict__ attn_out) {
  __shared__ __align__(16) half_t Ks[64 * 136];   // 272B stride: 2-way (free)
  __shared__ __align__(16) half_t Ps[4 * 16 * 72];

  const int tid = threadIdx.x;
  const int wave = tid >> 6;
  const int lane = tid & 63;
  const int quad = lane >> 4;
  const int l16 = lane & 15;

  // XCD-chunked swizzle: all 32 q-chunks of a head land on ONE XCD's L2.
  // (1024 % 8 == 0 -> bijective)
  const int wg = blockIdx.x + 32 * (blockIdx.y + Hh * blockIdx.z);
  const int v = (wg & 7) * (NBLK / 8) + (wg >> 3);
  const int q0 = (v & 31) * 64;
  const int bh = v >> 5;            // 0 .. B*H-1
  const int bidx = bh >> 4;         // batch index (Hh == 16)

  const half_t* Qg = Qh + ((size_t)bh * Ss + q0) * Dd;
  const half_t* Kg = Kh + (size_t)bh * Ss * Dd;
  const half_t* Vtg = Vt + (size_t)bh * Dd * Ss;
  const u64* Mg = Mb + ((size_t)bidx * Ss + q0) * NWrd;

  // Q A-fragments straight from global (one-time 16KB/block)
  const int arow = 16 * wave + l16;
  halfx8 qa[4];
#pragma unroll
  for (int ks = 0; ks < 4; ++ks)
    qa[ks] = *(const halfx8*)(Qg + (size_t)arow * Dd + ks * 32 + quad * 8);

  const int lrow = 16 * wave + quad * 4;  // local C-layout row base
  const int qrow = q0 + lrow;             // global (within head)
  const u64* Mrow = Mg + (size_t)lrow * NWrd;
  float lacc[4] = {0.f, 0.f, 0.f, 0.f};

  // staging decomposition: 256 threads x halfx8 = 4KB -> 4 rounds for 16KB tile
  const int s_r = tid >> 4;           // base row 0..15
  const int s_c = (tid & 15) << 3;    // col halves 0..120

  // prefetch tile 0 into registers
  halfx8 kpre[4];
#pragma unroll
  for (int it = 0; it < 4; ++it)
    kpre[it] = *(const halfx8*)(Kg + (size_t)(s_r + it * 16) * Dd + s_c);

  // -------- pass 1: per-lane partial row sums of exp --------
  for (int kt = 0; kt < NWrd; ++kt) {
    const int k0 = kt * 64;
    __syncthreads();  // previous tile's compute done -> Ks free
#pragma unroll
    for (int it = 0; it < 4; ++it)
      *(halfx8*)&Ks[(s_r + it * 16) * 136 + s_c] = kpre[it];
    if (kt + 1 < NWrd) {  // issue next tile's loads; latency hides under compute
#pragma unroll
      for (int it = 0; it < 4; ++it)
        kpre[it] = *(const halfx8*)(Kg + (size_t)(k0 + 64 + s_r + it * 16) * Dd + s_c);
    }
    u64 mw[4];
#pragma unroll
    for (int r = 0; r < 4; ++r) mw[r] = Mrow[(size_t)r * NWrd + kt];
    __syncthreads();  // Ks ready
#pragma unroll
    for (int nt = 0; nt < 4; ++nt) {
      floatx4 acc = {0.f, 0.f, 0.f, 0.f};
#pragma unroll
      for (int ks = 0; ks < 4; ++ks) {
        halfx8 bf = *(const halfx8*)&Ks[(nt * 16 + l16) * 136 + ks * 32 + quad * 8];
        acc = __builtin_amdgcn_mfma_f32_16x16x32_f16(qa[ks], bf, acc, 0, 0, 0);
      }
      const int sh = nt * 16 + l16;
#pragma unroll
      for (int r = 0; r < 4; ++r) {
        float e = ((mw[r] >> sh) & 1) ? __expf(acc[r]) : 0.0f;
        lacc[r] += e;  // reduce across l16 AFTER the loop
      }
    }
  }
  float inv[4];
#pragma unroll
  for (int r = 0; r < 4; ++r) {
    float s = lacc[r];
    s += __shfl_xor(s, 1);
    s += __shfl_xor(s, 2);
    s += __shfl_xor(s, 4);
    s += __shfl_xor(s, 8);
    inv[r] = 1.0f / s;
  }

  floatx4 cacc[8];
#pragma unroll
  for (int i = 0; i < 8; ++i) cacc[i] = (floatx4){0.f, 0.f, 0.f, 0.f};
  float* attn_row = attn_out + (size_t)bh * Ss * Ss + (size_t)qrow * Ss;

  // re-prefetch tile 0 for pass 2
#pragma unroll
  for (int it = 0; it < 4; ++it)
    kpre[it] = *(const halfx8*)(Kg + (size_t)(s_r + it * 16) * Dd + s_c);

  // -------- pass 2: normalized attention out + fused PV --------
  for (int kt = 0; kt < NWrd; ++kt) {
    const int k0 = kt * 64;
    __syncthreads();
#pragma unroll
    for (int it = 0; it < 4; ++it)
      *(halfx8*)&Ks[(s_r + it * 16) * 136 + s_c] = kpre[it];
    if (kt + 1 < NWrd) {
#pragma unroll
      for (int it = 0; it < 4; ++it)
        kpre[it] = *(const halfx8*)(Kg + (size_t)(k0 + 64 + s_r + it * 16) * Dd + s_c);
    }
    u64 mw[4];
#pragma unroll
    for (int r = 0; r < 4; ++r) mw[r] = Mrow[(size_t)r * NWrd + kt];
    __syncthreads();
#pragma unroll
    for (int nt = 0; nt < 4; ++nt) {
      floatx4 acc = {0.f, 0.f, 0.f, 0.f};
#pragma unroll
      for (int ks = 0; ks < 4; ++ks) {
        halfx8 bf = *(const halfx8*)&Ks[(nt * 16 + l16) * 136 + ks * 32 + quad * 8];
        acc = __builtin_amdgcn_mfma_f32_16x16x32_f16(qa[ks], bf, acc, 0, 0, 0);
      }
      const int sh = nt * 16 + l16;
#pragma unroll
      for (int r = 0; r < 4; ++r) {
        float p = ((mw[r] >> sh) & 1) ? __expf(acc[r]) * inv[r] : 0.0f;
        __builtin_nontemporal_store(p, &attn_row[(size_t)r * Ss + k0 + sh]);
        Ps[wave * (16 * 72) + (quad * 4 + r) * 72 + sh] = (half_t)p;
      }
    }
    halfx8 pa0 = *(const halfx8*)&Ps[wave * (16 * 72) + l16 * 72 + quad * 8];
    halfx8 pa1 = *(const halfx8*)&Ps[wave * (16 * 72) + l16 * 72 + 32 + quad * 8];
    // V B-fragments direct from global: same 64B-line count as a coalesced
    // staging pass, tile is L2-resident (shared by all 32 q-blocks of the head)
#pragma unroll
    for (int nt2 = 0; nt2 < 8; ++nt2) {
      const half_t* vrow = Vtg + (size_t)(nt2 * 16 + l16) * Ss + k0 + quad * 8;
      halfx8 bv0 = *(const halfx8*)(vrow);
      cacc[nt2] = __builtin_amdgcn_mfma_f32_16x16x32_f16(pa0, bv0, cacc[nt2], 0, 0, 0);
      halfx8 bv1 = *(const halfx8*)(vrow + 32);
      cacc[nt2] = __builtin_amdgcn_mfma_f32_16x16x32_f16(pa1, bv1, cacc[nt2], 0, 0, 0);
    }
  }

  float* ctx = ctx_out + (size_t)bh * Ss * Dd;
#pragma unroll
  for (int nt2 = 0; nt2 < 8; ++nt2) {
#pragma unroll
    for (int r = 0; r < 4; ++r) {
      ctx[(size_t)(qrow + r) * Dd + nt2 * 16 + l16] = cacc[nt2][r];
    }
  }
}

extern "C" void kernel_launch(void* const* d_in, const int* in_sizes, int n_in,
                              void* d_out, int out_size, void* d_ws, size_t ws_size,
                              hipStream_t stream) {
  const float* Q = (const float*)d_in[0];
  const float* K = (const float*)d_in[1];
  const float* V = (const float*)d_in[2];
  const int* mask = (const int*)d_in[3];
  const float* scale = (const float*)d_in[4];
  float* ctx = (float*)d_out;
  float* attn = (float*)d_out + (size_t)Bb * Hh * Ss * Dd;

  const size_t nqk = (size_t)Bb * Hh * Ss * Dd;  // 8388608
  half_t* Qh = (half_t*)d_ws;
  half_t* Kh = Qh + nqk;
  half_t* Vt = Kh + nqk;
  u64* Mbits = (u64*)(Vt + nqk);  // 1 MB

  cvt_qk_kernel<<<nqk / (256 * 8), 256, 0, stream>>>(Q, K, scale, Qh, Kh);
  dim3 gt(Ss / 64, Dd / 64, Bb * Hh);
  vt_kernel<<<gt, 256, 0, stream>>>(V, Vt);
  mask_pack_kernel<<<((size_t)Bb * Ss * NWrd) / 4, 256, 0, stream>>>(mask, Mbits);
  dim3 gm(Ss / 64, Hh, Bb);
  attn_kernel<<<gm, 256, 0, stream>>>(Qh, Kh, Mbits, Vt, ctx, attn);
}